// Round 2
// baseline (990.246 us; speedup 1.0000x reference)
//
#include <hip/hip_runtime.h>

// Problem: B=256, S=512, I=H=O=256, L=64. Inputs/outputs fp32; internal compute bf16 MFMA.
typedef unsigned short u16;
typedef unsigned int   u32;
typedef __attribute__((ext_vector_type(8))) __bf16 bf16x8;  // 4 VGPR MFMA frag
typedef __attribute__((ext_vector_type(8))) u16    u16x8;
typedef __attribute__((ext_vector_type(4))) float  f32x4;
typedef __attribute__((ext_vector_type(4))) u32    u32x4;

#define MFMA16(a,b,c) __builtin_amdgcn_mfma_f32_16x16x32_bf16((a),(b),(c),0,0,0)

__device__ __forceinline__ float b2f(u16 u){ u32 x = ((u32)u) << 16; return __builtin_bit_cast(float, x); }
__device__ __forceinline__ u16 f2b(float f){ // RNE f32->bf16
    u32 b = __builtin_bit_cast(u32, f);
    b += 0x7FFFu + ((b >> 16) & 1u);
    return (u16)(b >> 16);
}
__device__ __forceinline__ float tanh_fast(float x){ // 1 - 2/(e^{2x}+1); saturates to +-1
    float e = __builtin_amdgcn_exp2f(x * 2.8853900817779268f);
    return 1.0f - 2.0f * __builtin_amdgcn_rcpf(e + 1.0f);
}
__device__ __forceinline__ float sigm_fast(float x){
    float e = __builtin_amdgcn_exp2f(x * -1.4426950408889634f);
    return __builtin_amdgcn_rcpf(1.0f + e);
}

// ---------------- K1: xpre[b*512+t][n] = bf16( x[b][t][:] @ W1x + (b1x + b1a) ) ----------------
__global__ __launch_bounds__(256, 2) void k1_xw(const float* __restrict__ x, const float* __restrict__ w1x,
                                               const float* __restrict__ b1x, const float* __restrict__ b1a,
                                               u16* __restrict__ xpre)
{
    const int tid = threadIdx.x, lane = tid & 63, w = tid >> 6;
    const int l15 = lane & 15, q = lane >> 4;
    const int cw = w * 64;
    const f32x4 zero = {0.f, 0.f, 0.f, 0.f};

    bf16x8 bw[4][8];                                // W1x fragments (fp32 -> bf16 once)
    float bias[4];
    #pragma unroll
    for (int nt = 0; nt < 4; ++nt){
        const int n = cw + nt * 16 + l15;
        bias[nt] = b1x[n] + b1a[n];
        #pragma unroll
        for (int ks = 0; ks < 8; ++ks){
            u16x8 t;
            #pragma unroll
            for (int j = 0; j < 8; ++j) t[j] = f2b(w1x[(ks * 32 + q * 8 + j) * 256 + n]);
            bw[nt][ks] = __builtin_bit_cast(bf16x8, t);
        }
    }

    for (int blk = 0; blk < 16; ++blk){
        const int r0 = (blockIdx.x * 16 + blk) * 16;
        bf16x8 av[8];
        #pragma unroll
        for (int ks = 0; ks < 8; ++ks){
            const float* p = x + (size_t)(r0 + l15) * 256 + ks * 32 + q * 8;
            f32x4 v0 = *(const f32x4*)(p);
            f32x4 v1 = *(const f32x4*)(p + 4);
            u16x8 t;
            #pragma unroll
            for (int j = 0; j < 4; ++j){ t[j] = f2b(v0[j]); t[4 + j] = f2b(v1[j]); }
            av[ks] = __builtin_bit_cast(bf16x8, t);
        }
        f32x4 acc[4];
        #pragma unroll
        for (int nt = 0; nt < 4; ++nt) acc[nt] = zero;
        #pragma unroll
        for (int ks = 0; ks < 8; ++ks)
            #pragma unroll
            for (int nt = 0; nt < 4; ++nt)
                acc[nt] = MFMA16(av[ks], bw[nt][ks], acc[nt]);
        #pragma unroll
        for (int nt = 0; nt < 4; ++nt)
            #pragma unroll
            for (int r = 0; r < 4; ++r)
                xpre[(size_t)(r0 + q * 4 + r) * 256 + cw + nt * 16 + l15] = f2b(acc[nt][r] + bias[nt]);
    }
}

// ---------------- K2: encoder recurrence, 512 steps, 16 wgs x 16 batch rows ----------------
__global__ __launch_bounds__(256, 1) void k2_enc(const float* __restrict__ w1a, const u16* __restrict__ xpre,
                                                u16* __restrict__ alast)
{
    __shared__ __align__(16) u16 st[2][16][264];    // ping-pong bf16 state, padded
    const int tid = threadIdx.x, lane = tid & 63, w = tid >> 6;
    const int l15 = lane & 15, q = lane >> 4;
    const int cw = w * 64, b0 = blockIdx.x * 16;
    const f32x4 zero = {0.f, 0.f, 0.f, 0.f};

    bf16x8 bw[4][8];                                // W1a fragments, register-resident 512 steps
    #pragma unroll
    for (int nt = 0; nt < 4; ++nt){
        const int n = cw + nt * 16 + l15;
        #pragma unroll
        for (int ks = 0; ks < 8; ++ks){
            u16x8 t;
            #pragma unroll
            for (int j = 0; j < 8; ++j) t[j] = f2b(w1a[(ks * 32 + q * 8 + j) * 256 + n]);
            bw[nt][ks] = __builtin_bit_cast(bf16x8, t);
        }
    }
    for (int i = tid; i < 2 * 16 * 264; i += 256) (&st[0][0][0])[i] = 0;  // a0 = 0 (both buffers)
    __syncthreads();

    u32 xoff[16];
    #pragma unroll
    for (int nt = 0; nt < 4; ++nt)
        #pragma unroll
        for (int r = 0; r < 4; ++r)
            xoff[nt * 4 + r] = (u32)(b0 + q * 4 + r) * 512u * 256u + cw + nt * 16 + l15;

    u16 cur[16], nxt[16];
    #pragma unroll
    for (int i = 0; i < 16; ++i) cur[i] = xpre[xoff[i]];

    int p = 0;
    for (int t = 0; t < 512; ++t){
        const u32 tn = (u32)(t < 511 ? t + 1 : 511) * 256u;
        #pragma unroll
        for (int i = 0; i < 16; ++i) nxt[i] = xpre[xoff[i] + tn];   // prefetch, consumed next iter

        bf16x8 av[8];
        #pragma unroll
        for (int ks = 0; ks < 8; ++ks)
            av[ks] = *(const bf16x8*)&st[p][l15][ks * 32 + q * 8];
        f32x4 acc[4];
        #pragma unroll
        for (int nt = 0; nt < 4; ++nt) acc[nt] = zero;
        #pragma unroll
        for (int ks = 0; ks < 8; ++ks)
            #pragma unroll
            for (int nt = 0; nt < 4; ++nt)
                acc[nt] = MFMA16(av[ks], bw[nt][ks], acc[nt]);
        #pragma unroll
        for (int nt = 0; nt < 4; ++nt)
            #pragma unroll
            for (int r = 0; r < 4; ++r){
                float v = acc[nt][r] + b2f(cur[nt * 4 + r]);
                st[p ^ 1][q * 4 + r][cw + nt * 16 + l15] = f2b(tanh_fast(v));
            }
        #pragma unroll
        for (int i = 0; i < 16; ++i) cur[i] = nxt[i];
        __syncthreads();                             // single barrier/step (ping-pong)
        p ^= 1;
    }
    {
        const int row = tid >> 4, c0 = (tid & 15) * 16;
        #pragma unroll
        for (int j = 0; j < 2; ++j)
            *(u32x4*)(alast + (size_t)(b0 + row) * 256 + c0 + j * 8) = *(const u32x4*)&st[p][row][c0 + j * 8];
    }
}

// ---------------- K3: y0 + 64 decoder steps, 16 wgs; fp32 output ----------------
__global__ __launch_bounds__(256, 1) void k3_dec(const float* __restrict__ w2x, const float* __restrict__ b2x,
                                                const float* __restrict__ w2a, const float* __restrict__ b2a,
                                                const float* __restrict__ wy,  const float* __restrict__ by,
                                                const u16* __restrict__ alast, float* __restrict__ out)
{
    __shared__ __align__(16) u16 st[2][16][264];
    __shared__ __align__(16) u16 y0s[16][264];
    const int tid = threadIdx.x, lane = tid & 63, w = tid >> 6;
    const int l15 = lane & 15, q = lane >> 4;
    const int cw = w * 64, b0 = blockIdx.x * 16;
    const f32x4 zero = {0.f, 0.f, 0.f, 0.f};

    bf16x8 bwa[4][8], bwy[4][8];
    float bias2[4], biasy[4];
    #pragma unroll
    for (int nt = 0; nt < 4; ++nt){
        const int n = cw + nt * 16 + l15;
        bias2[nt] = b2x[n] + b2a[n];
        biasy[nt] = by[n];
        #pragma unroll
        for (int ks = 0; ks < 8; ++ks){
            u16x8 ta, ty;
            #pragma unroll
            for (int j = 0; j < 8; ++j){
                const int kk = (ks * 32 + q * 8 + j) * 256 + n;
                ta[j] = f2b(w2a[kk]); ty[j] = f2b(wy[kk]);
            }
            bwa[nt][ks] = __builtin_bit_cast(bf16x8, ta);
            bwy[nt][ks] = __builtin_bit_cast(bf16x8, ty);
        }
    }
    {
        const int row = tid >> 4, c0 = (tid & 15) * 16;
        #pragma unroll
        for (int j = 0; j < 2; ++j)
            *(u32x4*)&st[0][row][c0 + j * 8] = *(const u32x4*)(alast + (size_t)(b0 + row) * 256 + c0 + j * 8);
    }
    __syncthreads();

    {   // y0 = sigmoid(a_last @ Wy + by), rounded to bf16 for the W2x injection GEMM
        bf16x8 av[8];
        #pragma unroll
        for (int ks = 0; ks < 8; ++ks) av[ks] = *(const bf16x8*)&st[0][l15][ks * 32 + q * 8];
        f32x4 acc[4];
        #pragma unroll
        for (int nt = 0; nt < 4; ++nt) acc[nt] = zero;
        #pragma unroll
        for (int ks = 0; ks < 8; ++ks)
            #pragma unroll
            for (int nt = 0; nt < 4; ++nt) acc[nt] = MFMA16(av[ks], bwy[nt][ks], acc[nt]);
        #pragma unroll
        for (int nt = 0; nt < 4; ++nt)
            #pragma unroll
            for (int r = 0; r < 4; ++r)
                y0s[q * 4 + r][cw + nt * 16 + l15] = f2b(sigm_fast(acc[nt][r] + biasy[nt]));
    }
    __syncthreads();

    f32x4 inj[4];                                   // inj = y0 @ W2x (added only at i==0)
    #pragma unroll
    for (int nt = 0; nt < 4; ++nt) inj[nt] = zero;
    {
        bf16x8 av[8];
        #pragma unroll
        for (int ks = 0; ks < 8; ++ks) av[ks] = *(const bf16x8*)&y0s[l15][ks * 32 + q * 8];
        #pragma unroll
        for (int ks = 0; ks < 8; ++ks)
            #pragma unroll
            for (int nt = 0; nt < 4; ++nt){
                u16x8 t;
                #pragma unroll
                for (int j = 0; j < 8; ++j) t[j] = f2b(w2x[(ks * 32 + q * 8 + j) * 256 + cw + nt * 16 + l15]);
                inj[nt] = MFMA16(av[ks], __builtin_bit_cast(bf16x8, t), inj[nt]);
            }
    }

    int p = 0;
    for (int i = 0; i < 64; ++i){
        bf16x8 av[8];
        #pragma unroll
        for (int ks = 0; ks < 8; ++ks) av[ks] = *(const bf16x8*)&st[p][l15][ks * 32 + q * 8];
        f32x4 acc[4];
        #pragma unroll
        for (int nt = 0; nt < 4; ++nt) acc[nt] = zero;
        #pragma unroll
        for (int ks = 0; ks < 8; ++ks)
            #pragma unroll
            for (int nt = 0; nt < 4; ++nt) acc[nt] = MFMA16(av[ks], bwa[nt][ks], acc[nt]);
        #pragma unroll
        for (int nt = 0; nt < 4; ++nt)
            #pragma unroll
            for (int r = 0; r < 4; ++r){
                float v = acc[nt][r] + bias2[nt];
                if (i == 0) v += inj[nt][r];
                st[p ^ 1][q * 4 + r][cw + nt * 16 + l15] = f2b(tanh_fast(v));
            }
        __syncthreads();
        #pragma unroll
        for (int ks = 0; ks < 8; ++ks) av[ks] = *(const bf16x8*)&st[p ^ 1][l15][ks * 32 + q * 8];
        #pragma unroll
        for (int nt = 0; nt < 4; ++nt) acc[nt] = zero;
        #pragma unroll
        for (int ks = 0; ks < 8; ++ks)
            #pragma unroll
            for (int nt = 0; nt < 4; ++nt) acc[nt] = MFMA16(av[ks], bwy[nt][ks], acc[nt]);
        #pragma unroll
        for (int nt = 0; nt < 4; ++nt)
            #pragma unroll
            for (int r = 0; r < 4; ++r)
                out[(size_t)(b0 + q * 4 + r) * 64 * 256 + (size_t)i * 256 + cw + nt * 16 + l15]
                    = sigm_fast(acc[nt][r] + biasy[nt]);
        p ^= 1;
    }
}

extern "C" void kernel_launch(void* const* d_in, const int* in_sizes, int n_in,
                              void* d_out, int out_size, void* d_ws, size_t ws_size,
                              hipStream_t stream) {
    const float* x   = (const float*)d_in[0];
    const float* w1x = (const float*)d_in[1];
    const float* b1x = (const float*)d_in[2];
    const float* w1a = (const float*)d_in[3];
    const float* b1a = (const float*)d_in[4];
    const float* w2x = (const float*)d_in[5];
    const float* b2x = (const float*)d_in[6];
    const float* w2a = (const float*)d_in[7];
    const float* b2a = (const float*)d_in[8];
    const float* wy  = (const float*)d_in[9];
    const float* by  = (const float*)d_in[10];

    u16* xpre  = (u16*)d_ws;                       // [131072][256] bf16 = 64 MiB
    u16* alast = xpre + (size_t)131072 * 256;      // [256][256] bf16
    float* o   = (float*)d_out;                    // [256][64][256] fp32

    k1_xw <<<512, 256, 0, stream>>>(x, w1x, b1x, b1a, xpre);
    k2_enc<<<16,  256, 0, stream>>>(w1a, xpre, alast);
    k3_dec<<<16,  256, 0, stream>>>(w2x, b2x, w2a, b2a, wy, by, alast, o);
}

// Round 4
// 971.703 us; speedup vs baseline: 1.0191x; 1.0191x over previous
//
#include <hip/hip_runtime.h>

// B=256, S=512, I=H=O=256, L=64. Inputs/outputs fp32; internal bf16 MFMA.
// Structure: K1 precomputes xpre = x@W1x + b1x + b1a in K2's per-lane fragment
// order. K2/K3: 512-thread wgs, 8 waves = 2/SIMD, 2-way K-split with LDS
// partial exchange -> halved epilogue per wave + latency overlap.
typedef unsigned short u16;
typedef unsigned int   u32;
typedef __attribute__((ext_vector_type(8))) __bf16 bf16x8;
typedef __attribute__((ext_vector_type(8))) u16    u16x8;
typedef __attribute__((ext_vector_type(4))) float  f32x4;
typedef __attribute__((ext_vector_type(4))) u32    u32x4;
typedef __attribute__((ext_vector_type(2))) u32    u32x2;

#define MFMA16(a,b,c) __builtin_amdgcn_mfma_f32_16x16x32_bf16((a),(b),(c),0,0,0)

__device__ __forceinline__ float b2f(u32 hi_or_lo){ return __builtin_bit_cast(float, hi_or_lo); }
__device__ __forceinline__ u16 f2b(float f){ // RNE f32->bf16
    u32 b = __builtin_bit_cast(u32, f);
    b += 0x7FFFu + ((b >> 16) & 1u);
    return (u16)(b >> 16);
}
__device__ __forceinline__ u32 pkbf(float a, float b){ // two f32 -> packed bf16x2 (lo=a), RNE
    return ((u32)f2b(b) << 16) | (u32)f2b(a);
}
__device__ __forceinline__ float tanh_fast(float x){
    float e = __builtin_amdgcn_exp2f(x * 2.8853900817779268f);
    return 1.0f - 2.0f * __builtin_amdgcn_rcpf(e + 1.0f);
}
__device__ __forceinline__ float sigm_fast(float x){
    float e = __builtin_amdgcn_exp2f(x * -1.4426950408889634f);
    return __builtin_amdgcn_rcpf(1.0f + e);
}

// xpre element addr (u16 units): ((t*16+bg)*512 + wid*64 + (16q+l15))*8 + slot
// wid = colblk + 4*khalf of consumer; slot = nt01*4 + r (r = batch%4).

// ---------------- K1: grid=512 (t), 256 thr. Tiles = 16 batches x 64 cols at fixed t ----------------
__global__ __launch_bounds__(256, 1) void k1_xw(const float* __restrict__ x, const float* __restrict__ w1x,
                                               const float* __restrict__ b1x, const float* __restrict__ b1a,
                                               u16* __restrict__ xpre)
{
    const int t = blockIdx.x;
    const int tid = threadIdx.x, lane = tid & 63, w = tid >> 6;
    const int l15 = lane & 15, q = lane >> 4;
    const int cw = w * 64;
    const f32x4 zero = {0.f, 0.f, 0.f, 0.f};

    bf16x8 bw[4][8];                                 // W1x B-frags, full K
    float bias[4];
    #pragma unroll
    for (int nt = 0; nt < 4; ++nt){
        const int n = cw + nt * 16 + l15;
        bias[nt] = b1x[n] + b1a[n];
        #pragma unroll
        for (int ks = 0; ks < 8; ++ks){
            u16x8 tt;
            #pragma unroll
            for (int j = 0; j < 8; ++j) tt[j] = f2b(w1x[(ks * 32 + q * 8 + j) * 256 + n]);
            bw[nt][ks] = __builtin_bit_cast(bf16x8, tt);
        }
    }

    for (int blk = 0; blk < 16; ++blk){
        const int b0r = blk * 16;                    // batches b0r..b0r+15 at time t
        bf16x8 av[8];
        #pragma unroll
        for (int ks = 0; ks < 8; ++ks){
            const float* p = x + ((size_t)(b0r + l15) * 512 + t) * 256 + ks * 32 + q * 8;
            f32x4 v0 = *(const f32x4*)p;
            f32x4 v1 = *(const f32x4*)(p + 4);
            u32x4 dd = { pkbf(v0[0], v0[1]), pkbf(v0[2], v0[3]),
                         pkbf(v1[0], v1[1]), pkbf(v1[2], v1[3]) };
            av[ks] = __builtin_bit_cast(bf16x8, dd);
        }
        f32x4 acc[4];
        #pragma unroll
        for (int nt = 0; nt < 4; ++nt) acc[nt] = zero;
        #pragma unroll
        for (int ks = 0; ks < 8; ++ks)
            #pragma unroll
            for (int nt = 0; nt < 4; ++nt)
                acc[nt] = MFMA16(av[ks], bw[nt][ks], acc[nt]);
        #pragma unroll
        for (int nt = 0; nt < 4; ++nt){
            float v0 = acc[nt][0] + bias[nt], v1 = acc[nt][1] + bias[nt];
            float v2 = acc[nt][2] + bias[nt], v3 = acc[nt][3] + bias[nt];
            u32x2 dd = { pkbf(v0, v1), pkbf(v2, v3) };  // slots r=0..3 consecutive
            const size_t a16 = (((size_t)t * 16 + blk) * 512 + (size_t)(w + 4 * (nt >> 1)) * 64
                                + q * 16 + l15) * 8 + (nt & 1) * 4;
            *(u32x2*)(xpre + a16) = dd;
        }
    }
}

// K-split matmul helper: 8 waves; waves w and w^4 pair on a 16x64 tile (K halves),
// exchange non-owned partials via scr, return owner's two reduced 16x16 tiles.
__device__ __forceinline__ void mm_ksplit(const u16 (*stp)[264], const bf16x8 (*bw)[4],
                                          float (*scr)[64][12],
                                          int w, int lane, int l15, int q, int kh,
                                          f32x4& o0, f32x4& o1)
{
    bf16x8 av[4];
    #pragma unroll
    for (int ksl = 0; ksl < 4; ++ksl)
        av[ksl] = *(const bf16x8*)&stp[l15][kh * 128 + ksl * 32 + q * 8];
    const f32x4 zero = {0.f, 0.f, 0.f, 0.f};
    f32x4 acc[4];
    #pragma unroll
    for (int nt = 0; nt < 4; ++nt) acc[nt] = zero;
    #pragma unroll
    for (int ksl = 0; ksl < 4; ++ksl)
        #pragma unroll
        for (int nt = 0; nt < 4; ++nt)
            acc[nt] = MFMA16(av[ksl], bw[nt][ksl], acc[nt]);
    // write the two tiles the partner owns
    *(f32x4*)&scr[w][lane][0] = kh ? acc[0] : acc[2];
    *(f32x4*)&scr[w][lane][4] = kh ? acc[1] : acc[3];
    __syncthreads();
    f32x4 p0 = *(const f32x4*)&scr[w ^ 4][lane][0];
    f32x4 p1 = *(const f32x4*)&scr[w ^ 4][lane][4];
    o0 = (kh ? acc[2] : acc[0]) + p0;
    o1 = (kh ? acc[3] : acc[1]) + p1;
}

// ---------------- K2: encoder, 16 wgs x 512 thr, 512 steps ----------------
__global__ __launch_bounds__(512) void k2_enc(const float* __restrict__ w1a, const u16* __restrict__ xpre,
                                              u16* __restrict__ alast)
{
    __shared__ __align__(16) u16 st[16][264];
    __shared__ __align__(16) float scr[8][64][12];
    const int tid = threadIdx.x, lane = tid & 63, w = tid >> 6;
    const int l15 = lane & 15, q = lane >> 4;
    const int kh = w >> 2, wc = w & 3;
    const int bg = blockIdx.x;
    const int colb = wc * 64 + kh * 32;              // owner cols colb + nt01*16 + l15

    bf16x8 bw[4][4];                                 // W1a B-frags, K-half
    #pragma unroll
    for (int nt = 0; nt < 4; ++nt){
        const int n = wc * 64 + nt * 16 + l15;
        #pragma unroll
        for (int ksl = 0; ksl < 4; ++ksl){
            const int k0 = kh * 128 + ksl * 32 + q * 8;
            u16x8 tt;
            #pragma unroll
            for (int j = 0; j < 8; ++j) tt[j] = f2b(w1a[(k0 + j) * 256 + n]);
            bw[nt][ksl] = __builtin_bit_cast(bf16x8, tt);
        }
    }
    for (int i = tid; i < 16 * 264; i += 512) (&st[0][0])[i] = 0;   // a0 = 0
    __syncthreads();

    const u16* xp = xpre + ((size_t)bg * 512 + (size_t)w * 64 + lane) * 8;  // + t*65536
    u32x4 cur = *(const u32x4*)xp;
    u32x4 nx1 = *(const u32x4*)(xp + 65536);

    for (int t = 0; t < 512; ++t){
        const int tp = (t + 2 < 512) ? t + 2 : 511;
        u32x4 nx2 = *(const u32x4*)(xp + (size_t)tp * 65536);       // 2-deep prefetch

        f32x4 o0, o1;
        mm_ksplit(st, bw, scr, w, lane, l15, q, kh, o0, o1);        // barrier inside

        #pragma unroll
        for (int nt01 = 0; nt01 < 2; ++nt01){
            const f32x4 o = nt01 ? o1 : o0;
            #pragma unroll
            for (int r = 0; r < 4; ++r){
                const u32 d = cur[nt01 * 2 + (r >> 1)];
                const float xv = (r & 1) ? b2f(d & 0xFFFF0000u) : b2f(d << 16);
                st[q * 4 + r][colb + nt01 * 16 + l15] = f2b(tanh_fast(o[r] + xv));
            }
        }
        cur = nx1; nx1 = nx2;
        __syncthreads();
    }
    {
        const int row = tid >> 5, c0 = (tid & 31) * 8;
        *(u32x4*)(alast + (size_t)(bg * 16 + row) * 256 + c0) = *(const u32x4*)&st[row][c0];
    }
}

// ---------------- K3: y0 + inj + 64 decoder steps, 16 wgs x 512 thr ----------------
__global__ __launch_bounds__(512) void k3_dec(const float* __restrict__ w2x, const float* __restrict__ b2x,
                                              const float* __restrict__ w2a, const float* __restrict__ b2a,
                                              const float* __restrict__ wy,  const float* __restrict__ by,
                                              const u16* __restrict__ alast, float* __restrict__ out)
{
    __shared__ __align__(16) u16 st[16][264];
    __shared__ __align__(16) u16 y0s[16][264];
    __shared__ __align__(16) float scr[8][64][12];
    const int tid = threadIdx.x, lane = tid & 63, w = tid >> 6;
    const int l15 = lane & 15, q = lane >> 4;
    const int kh = w >> 2, wc = w & 3;
    const int bg = blockIdx.x;
    const int colb = wc * 64 + kh * 32;

    float bias2o[2], biasyo[2];
    #pragma unroll
    for (int nt01 = 0; nt01 < 2; ++nt01){
        const int col = colb + nt01 * 16 + l15;
        bias2o[nt01] = b2x[col] + b2a[col];
        biasyo[nt01] = by[col];
    }

    bf16x8 bwa[4][4], bwy[4][4];
    #pragma unroll
    for (int nt = 0; nt < 4; ++nt){
        const int n = wc * 64 + nt * 16 + l15;
        #pragma unroll
        for (int ksl = 0; ksl < 4; ++ksl){
            const int k0 = kh * 128 + ksl * 32 + q * 8;
            u16x8 ta, ty;
            #pragma unroll
            for (int j = 0; j < 8; ++j){
                const int kk = (k0 + j) * 256 + n;
                ta[j] = f2b(w2a[kk]); ty[j] = f2b(wy[kk]);
            }
            bwa[nt][ksl] = __builtin_bit_cast(bf16x8, ta);
            bwy[nt][ksl] = __builtin_bit_cast(bf16x8, ty);
        }
    }
    {
        const int row = tid >> 5, c0 = (tid & 31) * 8;
        *(u32x4*)&st[row][c0] = *(const u32x4*)(alast + (size_t)(bg * 16 + row) * 256 + c0);
    }
    __syncthreads();

    // y0 = sigmoid(a_last @ Wy + by) -> y0s (bf16)
    {
        f32x4 o0, o1;
        mm_ksplit(st, bwy, scr, w, lane, l15, q, kh, o0, o1);
        #pragma unroll
        for (int nt01 = 0; nt01 < 2; ++nt01){
            const f32x4 o = nt01 ? o1 : o0;
            #pragma unroll
            for (int r = 0; r < 4; ++r)
                y0s[q * 4 + r][colb + nt01 * 16 + l15] = f2b(sigm_fast(o[r] + biasyo[nt01]));
        }
    }
    __syncthreads();

    // inj = y0 @ W2x (owner keeps its two tiles in regs)
    f32x4 inj0, inj1;
    {
        bf16x8 bx[4][4];
        #pragma unroll
        for (int nt = 0; nt < 4; ++nt){
            const int n = wc * 64 + nt * 16 + l15;
            #pragma unroll
            for (int ksl = 0; ksl < 4; ++ksl){
                const int k0 = kh * 128 + ksl * 32 + q * 8;
                u16x8 tt;
                #pragma unroll
                for (int j = 0; j < 8; ++j) tt[j] = f2b(w2x[(k0 + j) * 256 + n]);
                bx[nt][ksl] = __builtin_bit_cast(bf16x8, tt);
            }
        }
        mm_ksplit(y0s, bx, scr, w, lane, l15, q, kh, inj0, inj1);
    }
    __syncthreads();   // all inj reads done before loop reuses scr

    for (int i = 0; i < 64; ++i){
        // a = tanh(a@W2a + b2x + b2a [+ inj at i==0])
        {
            f32x4 o0, o1;
            mm_ksplit(st, bwa, scr, w, lane, l15, q, kh, o0, o1);
            #pragma unroll
            for (int nt01 = 0; nt01 < 2; ++nt01){
                const f32x4 o = nt01 ? o1 : o0;
                const f32x4 inj = nt01 ? inj1 : inj0;
                #pragma unroll
                for (int r = 0; r < 4; ++r){
                    float v = o[r] + bias2o[nt01];
                    if (i == 0) v += inj[r];
                    st[q * 4 + r][colb + nt01 * 16 + l15] = f2b(tanh_fast(v));
                }
            }
        }
        __syncthreads();
        // y = sigmoid(a@Wy + by) -> out (fp32)
        {
            f32x4 o0, o1;
            mm_ksplit(st, bwy, scr, w, lane, l15, q, kh, o0, o1);
            #pragma unroll
            for (int nt01 = 0; nt01 < 2; ++nt01){
                const f32x4 o = nt01 ? o1 : o0;
                #pragma unroll
                for (int r = 0; r < 4; ++r)
                    out[((size_t)(bg * 16 + q * 4 + r) * 64 + i) * 256 + colb + nt01 * 16 + l15]
                        = sigm_fast(o[r] + biasyo[nt01]);
            }
        }
        __syncthreads();
    }
}

extern "C" void kernel_launch(void* const* d_in, const int* in_sizes, int n_in,
                              void* d_out, int out_size, void* d_ws, size_t ws_size,
                              hipStream_t stream) {
    const float* x   = (const float*)d_in[0];
    const float* w1x = (const float*)d_in[1];
    const float* b1x = (const float*)d_in[2];
    const float* w1a = (const float*)d_in[3];
    const float* b1a = (const float*)d_in[4];
    const float* w2x = (const float*)d_in[5];
    const float* b2x = (const float*)d_in[6];
    const float* w2a = (const float*)d_in[7];
    const float* b2a = (const float*)d_in[8];
    const float* wy  = (const float*)d_in[9];
    const float* by  = (const float*)d_in[10];

    u16* xpre  = (u16*)d_ws;                       // 33.5M u16 = 64 MiB, fragment-ordered
    u16* alast = xpre + (size_t)512 * 16 * 512 * 8;
    float* o   = (float*)d_out;

    k1_xw <<<512, 256, 0, stream>>>(x, w1x, b1x, b1a, xpre);
    k2_enc<<<16,  512, 0, stream>>>(w1a, xpre, alast);
    k3_dec<<<16,  512, 0, stream>>>(w2x, b2x, w2a, b2a, wy, by, alast, o);
}

// Round 5
// 759.402 us; speedup vs baseline: 1.3040x; 1.2796x over previous
//
#include <hip/hip_runtime.h>

// B=256, S=512, I=H=O=256, L=64. fp32 in/out; bf16 MFMA internally.
// k1: xpre = C*(x@W1x + b1x + b1a) in K2 fragment order (C = 2*log2e baked in).
// k2: encoder, 16 wgs x 4 waves, full-K per wave, ONE raw lgkm-only barrier/step.
// k3pre: y0 = sigmoid(alast@Wy+by); inj = C*(y0@W2x).
// k3a: 64-step decoder recurrence, stores all states to astate (aliases xpre ws).
// k3b: out = sigmoid(astate@Wy + by) as one parallel GEMM (16384x256 @ 256x256).
typedef unsigned short u16;
typedef unsigned int   u32;
typedef __attribute__((ext_vector_type(8))) __bf16 bf16x8;
typedef __attribute__((ext_vector_type(8))) u16    u16x8;
typedef __attribute__((ext_vector_type(4))) float  f32x4;
typedef __attribute__((ext_vector_type(4))) u32    u32x4;
typedef __attribute__((ext_vector_type(2))) u32    u32x2;

#define MFMA16(a,b,c) __builtin_amdgcn_mfma_f32_16x16x32_bf16((a),(b),(c),0,0,0)
#define C_TANH 2.8853900817779268f   /* 2*log2(e): tanh(v)=1-2/(2^(C*v)+1) */
#define NL2E  -1.4426950408889634f   /* -log2(e): sigm(u)=1/(1+2^(NL2E*u)) */

__device__ __forceinline__ float ubit(u32 x){ return __builtin_bit_cast(float, x); }
__device__ __forceinline__ u16 f2b(float f){ // RNE f32->bf16 (prep paths)
    u32 b = __builtin_bit_cast(u32, f);
    b += 0x7FFFu + ((b >> 16) & 1u);
    return (u16)(b >> 16);
}
__device__ __forceinline__ u32 pkbf(float a, float b){ return ((u32)f2b(b) << 16) | (u32)f2b(a); }
// Barrier that drains ONLY LDS counters -- vmem (prefetch/stores) stays in flight.
__device__ __forceinline__ void bar_lds(){ __asm__ volatile("s_waitcnt lgkmcnt(0)\n\ts_barrier" ::: "memory"); }

// ---------------- K1: xpre (scaled), fragment-ordered ----------------
__global__ __launch_bounds__(256, 1) void k1_xw(const float* __restrict__ x, const float* __restrict__ w1x,
                                               const float* __restrict__ b1x, const float* __restrict__ b1a,
                                               u16* __restrict__ xpre)
{
    const int t = blockIdx.x;
    const int tid = threadIdx.x, lane = tid & 63, w = tid >> 6;
    const int l15 = lane & 15, q = lane >> 4;
    const int cw = w * 64;

    bf16x8 bw[4][8];
    float bias[4];
    #pragma unroll
    for (int nt = 0; nt < 4; ++nt){
        const int n = cw + nt * 16 + l15;
        bias[nt] = (b1x[n] + b1a[n]) * C_TANH;
        #pragma unroll
        for (int ks = 0; ks < 8; ++ks){
            u16x8 tt;
            #pragma unroll
            for (int j = 0; j < 8; ++j) tt[j] = f2b(w1x[(ks * 32 + q * 8 + j) * 256 + n] * C_TANH);
            bw[nt][ks] = __builtin_bit_cast(bf16x8, tt);
        }
    }

    for (int blk = 0; blk < 16; ++blk){
        const int b0r = blk * 16;
        bf16x8 av[8];
        #pragma unroll
        for (int ks = 0; ks < 8; ++ks){
            const float* p = x + ((size_t)(b0r + l15) * 512 + t) * 256 + ks * 32 + q * 8;
            f32x4 v0 = *(const f32x4*)p;
            f32x4 v1 = *(const f32x4*)(p + 4);
            u32x4 dd = { pkbf(v0[0], v0[1]), pkbf(v0[2], v0[3]),
                         pkbf(v1[0], v1[1]), pkbf(v1[2], v1[3]) };
            av[ks] = __builtin_bit_cast(bf16x8, dd);
        }
        f32x4 acc[4];
        #pragma unroll
        for (int nt = 0; nt < 4; ++nt) acc[nt] = (f32x4){bias[nt], bias[nt], bias[nt], bias[nt]};
        #pragma unroll
        for (int ks = 0; ks < 8; ++ks)
            #pragma unroll
            for (int nt = 0; nt < 4; ++nt)
                acc[nt] = MFMA16(av[ks], bw[nt][ks], acc[nt]);
        #pragma unroll
        for (int nt = 0; nt < 4; ++nt){
            u32x2 dd = { pkbf(acc[nt][0], acc[nt][1]), pkbf(acc[nt][2], acc[nt][3]) };
            const size_t a16 = (((size_t)t * 16 + blk) * 512 + (size_t)(w + 4 * (nt >> 1)) * 64
                                + q * 16 + l15) * 8 + (nt & 1) * 4;
            *(u32x2*)(xpre + a16) = dd;
        }
    }
}

// ---------------- K2: encoder, 16 wgs x 256 thr, full-K waves, 1 raw barrier/step ----------------
__global__ __launch_bounds__(256, 1) void k2_enc(const float* __restrict__ w1a, const u16* __restrict__ xpre,
                                                u16* __restrict__ alast)
{
    __shared__ __align__(16) u16 st[2][16][264];
    const int tid = threadIdx.x, lane = tid & 63, w = tid >> 6;
    const int l15 = lane & 15, q = lane >> 4;
    const int bg = blockIdx.x;

    bf16x8 bw[4][8];                               // C-scaled W1a, full K, register-resident
    #pragma unroll
    for (int nt = 0; nt < 4; ++nt){
        const int n = w * 64 + nt * 16 + l15;
        #pragma unroll
        for (int ks = 0; ks < 8; ++ks){
            u16x8 tt;
            #pragma unroll
            for (int j = 0; j < 8; ++j) tt[j] = f2b(w1a[(ks * 32 + q * 8 + j) * 256 + n] * C_TANH);
            bw[nt][ks] = __builtin_bit_cast(bf16x8, tt);
        }
    }
    for (int i = tid; i < 16 * 264; i += 256) (&st[0][0][0])[i] = 0;   // a0 = 0
    __syncthreads();

    const u16* xp0 = xpre + ((size_t)bg * 512 + (size_t)w * 64 + lane) * 8;   // tiles 0,1
    const u16* xp1 = xp0 + 2048;                                              // tiles 2,3
    u32x4 c0 = *(const u32x4*)xp0,            c1 = *(const u32x4*)xp1;
    u32x4 a0 = *(const u32x4*)(xp0 + 65536),  a1 = *(const u32x4*)(xp1 + 65536);

    const u16 (*sR)[264] = st[0];
    u16 (*sW)[264] = st[1];

    for (int t = 0; t < 512; ++t){
        const size_t tp = (size_t)((t + 2 < 512) ? t + 2 : 511) * 65536;
        u32x4 n0 = *(const u32x4*)(xp0 + tp);
        u32x4 n1 = *(const u32x4*)(xp1 + tp);

        bf16x8 av[8];
        #pragma unroll
        for (int ks = 0; ks < 8; ++ks)
            av[ks] = *(const bf16x8*)&sR[l15][ks * 32 + q * 8];

        f32x4 acc[4];                               // init = scaled xpre (saves the adds)
        #pragma unroll
        for (int nt = 0; nt < 4; ++nt){
            const u32x4 src = (nt < 2) ? c0 : c1;
            #pragma unroll
            for (int r = 0; r < 4; ++r){
                const u32 d = src[(nt & 1) * 2 + (r >> 1)];
                acc[nt][r] = ubit((r & 1) ? (d & 0xFFFF0000u) : (d << 16));
            }
        }
        #pragma unroll
        for (int ks = 0; ks < 8; ++ks)
            #pragma unroll
            for (int nt = 0; nt < 4; ++nt)
                acc[nt] = MFMA16(av[ks], bw[nt][ks], acc[nt]);

        #pragma unroll
        for (int nt = 0; nt < 4; ++nt)
            #pragma unroll
            for (int r = 0; r < 4; ++r){
                float e = __builtin_amdgcn_exp2f(acc[nt][r]);
                float s = 1.0f - 2.0f * __builtin_amdgcn_rcpf(e + 1.0f);
                u32 rb = __builtin_bit_cast(u32, s) + 0x8000u;   // round-away bf16
                sW[q * 4 + r][w * 64 + nt * 16 + l15] = (u16)(rb >> 16);
            }
        c0 = a0; c1 = a1; a0 = n0; a1 = n1;
        bar_lds();                                   // LDS-only drain; vmem stays in flight
        const u16 (*tmp)[264] = sR; sR = (const u16(*)[264])sW; sW = (u16(*)[264])tmp;
    }
    {
        const int row = tid >> 4, c = (tid & 15) * 16;
        #pragma unroll
        for (int j = 0; j < 2; ++j)
            *(u32x4*)(alast + (size_t)(bg * 16 + row) * 256 + c + j * 8) = *(const u32x4*)&sR[row][c + j * 8];
    }
}

// ---------------- K3pre: y0 + inj, 16 wgs x 256 thr ----------------
__global__ __launch_bounds__(256, 1) void k3_pre(const float* __restrict__ wy, const float* __restrict__ by,
                                                const float* __restrict__ w2x,
                                                const u16* __restrict__ alast, float* __restrict__ injws)
{
    __shared__ __align__(16) u16 st[16][264];
    __shared__ __align__(16) u16 y0s[16][264];
    const int tid = threadIdx.x, lane = tid & 63, w = tid >> 6;
    const int l15 = lane & 15, q = lane >> 4;
    const int bg = blockIdx.x;
    {
        const int row = tid >> 4, c = (tid & 15) * 16;
        #pragma unroll
        for (int j = 0; j < 2; ++j)
            *(u32x4*)&st[row][c + j * 8] = *(const u32x4*)(alast + (size_t)(bg * 16 + row) * 256 + c + j * 8);
    }
    __syncthreads();
    {   // y0 = sigm(alast@Wy+by), Wy scaled by -log2e
        bf16x8 bwy[4][8];
        float biasy[4];
        #pragma unroll
        for (int nt = 0; nt < 4; ++nt){
            const int n = w * 64 + nt * 16 + l15;
            biasy[nt] = by[n] * NL2E;
            #pragma unroll
            for (int ks = 0; ks < 8; ++ks){
                u16x8 tt;
                #pragma unroll
                for (int j = 0; j < 8; ++j) tt[j] = f2b(wy[(ks * 32 + q * 8 + j) * 256 + n] * NL2E);
                bwy[nt][ks] = __builtin_bit_cast(bf16x8, tt);
            }
        }
        bf16x8 av[8];
        #pragma unroll
        for (int ks = 0; ks < 8; ++ks) av[ks] = *(const bf16x8*)&st[l15][ks * 32 + q * 8];
        f32x4 acc[4];
        #pragma unroll
        for (int nt = 0; nt < 4; ++nt) acc[nt] = (f32x4){biasy[nt], biasy[nt], biasy[nt], biasy[nt]};
        #pragma unroll
        for (int ks = 0; ks < 8; ++ks)
            #pragma unroll
            for (int nt = 0; nt < 4; ++nt) acc[nt] = MFMA16(av[ks], bwy[nt][ks], acc[nt]);
        #pragma unroll
        for (int nt = 0; nt < 4; ++nt)
            #pragma unroll
            for (int r = 0; r < 4; ++r){
                float y = __builtin_amdgcn_rcpf(1.0f + __builtin_amdgcn_exp2f(acc[nt][r]));
                y0s[q * 4 + r][w * 64 + nt * 16 + l15] = f2b(y);
            }
    }
    __syncthreads();
    {   // inj = C * (y0 @ W2x)  (no bias)
        bf16x8 av[8];
        #pragma unroll
        for (int ks = 0; ks < 8; ++ks) av[ks] = *(const bf16x8*)&y0s[l15][ks * 32 + q * 8];
        f32x4 acc[4];
        #pragma unroll
        for (int nt = 0; nt < 4; ++nt) acc[nt] = (f32x4){0.f, 0.f, 0.f, 0.f};
        #pragma unroll
        for (int ks = 0; ks < 8; ++ks)
            #pragma unroll
            for (int nt = 0; nt < 4; ++nt){
                const int n = w * 64 + nt * 16 + l15;
                u16x8 tt;
                #pragma unroll
                for (int j = 0; j < 8; ++j) tt[j] = f2b(w2x[(ks * 32 + q * 8 + j) * 256 + n] * C_TANH);
                acc[nt] = MFMA16(av[ks], __builtin_bit_cast(bf16x8, tt), acc[nt]);
            }
        #pragma unroll
        for (int nt = 0; nt < 4; ++nt)
            *(f32x4*)(injws + ((size_t)bg * 1024 + (size_t)(w * 4 + nt) * 64 + lane) * 4) = acc[nt];
    }
}

// ---------------- K3a: decoder recurrence, stores all 64 states ----------------
__global__ __launch_bounds__(256, 1) void k3_rec(const float* __restrict__ w2a, const float* __restrict__ b2x,
                                                const float* __restrict__ b2a, const u16* __restrict__ alast,
                                                const float* __restrict__ injws, u16* __restrict__ astate)
{
    __shared__ __align__(16) u16 st[2][16][264];
    const int tid = threadIdx.x, lane = tid & 63, w = tid >> 6;
    const int l15 = lane & 15, q = lane >> 4;
    const int bg = blockIdx.x;

    bf16x8 bw[4][8];
    float bias2[4];
    #pragma unroll
    for (int nt = 0; nt < 4; ++nt){
        const int n = w * 64 + nt * 16 + l15;
        bias2[nt] = (b2x[n] + b2a[n]) * C_TANH;
        #pragma unroll
        for (int ks = 0; ks < 8; ++ks){
            u16x8 tt;
            #pragma unroll
            for (int j = 0; j < 8; ++j) tt[j] = f2b(w2a[(ks * 32 + q * 8 + j) * 256 + n] * C_TANH);
            bw[nt][ks] = __builtin_bit_cast(bf16x8, tt);
        }
    }
    f32x4 ini[4];
    #pragma unroll
    for (int nt = 0; nt < 4; ++nt){
        f32x4 inj = *(const f32x4*)(injws + ((size_t)bg * 1024 + (size_t)(w * 4 + nt) * 64 + lane) * 4);
        ini[nt] = inj + bias2[nt];                   // i==0 init; reset after first step
    }
    {
        const int row = tid >> 4, c = (tid & 15) * 16;
        #pragma unroll
        for (int j = 0; j < 2; ++j)
            *(u32x4*)&st[0][row][c + j * 8] = *(const u32x4*)(alast + (size_t)(bg * 16 + row) * 256 + c + j * 8);
    }
    __syncthreads();

    const u16 (*sR)[264] = st[0];
    u16 (*sW)[264] = st[1];

    for (int i = 0; i < 64; ++i){
        bf16x8 av[8];
        #pragma unroll
        for (int ks = 0; ks < 8; ++ks) av[ks] = *(const bf16x8*)&sR[l15][ks * 32 + q * 8];
        f32x4 acc[4];
        #pragma unroll
        for (int nt = 0; nt < 4; ++nt) acc[nt] = ini[nt];
        #pragma unroll
        for (int ks = 0; ks < 8; ++ks)
            #pragma unroll
            for (int nt = 0; nt < 4; ++nt) acc[nt] = MFMA16(av[ks], bw[nt][ks], acc[nt]);
        #pragma unroll
        for (int nt = 0; nt < 4; ++nt)
            #pragma unroll
            for (int r = 0; r < 4; ++r){
                float e = __builtin_amdgcn_exp2f(acc[nt][r]);
                float s = 1.0f - 2.0f * __builtin_amdgcn_rcpf(e + 1.0f);
                u32 rb = __builtin_bit_cast(u32, s) + 0x8000u;
                u16 v = (u16)(rb >> 16);
                sW[q * 4 + r][w * 64 + nt * 16 + l15] = v;
                astate[((size_t)i * 256 + bg * 16 + q * 4 + r) * 256 + w * 64 + nt * 16 + l15] = v;
            }
        if (i == 0){
            #pragma unroll
            for (int nt = 0; nt < 4; ++nt)
                ini[nt] = (f32x4){bias2[nt], bias2[nt], bias2[nt], bias2[nt]};
        }
        bar_lds();
        const u16 (*tmp)[264] = sR; sR = (const u16(*)[264])sW; sW = (u16(*)[264])tmp;
    }
}

// ---------------- K3b: out = sigm(astate@Wy + by), 256 wgs x 256 thr ----------------
__global__ __launch_bounds__(256, 1) void k3_out(const float* __restrict__ wy, const float* __restrict__ by,
                                                const u16* __restrict__ astate, float* __restrict__ out)
{
    const int tid = threadIdx.x, lane = tid & 63, w = tid >> 6;
    const int l15 = lane & 15, q = lane >> 4;

    bf16x8 bwy[4][8];
    float biasy[4];
    #pragma unroll
    for (int nt = 0; nt < 4; ++nt){
        const int n = w * 64 + nt * 16 + l15;
        biasy[nt] = by[n] * NL2E;
        #pragma unroll
        for (int ks = 0; ks < 8; ++ks){
            u16x8 tt;
            #pragma unroll
            for (int j = 0; j < 8; ++j) tt[j] = f2b(wy[(ks * 32 + q * 8 + j) * 256 + n] * NL2E);
            bwy[nt][ks] = __builtin_bit_cast(bf16x8, tt);
        }
    }
    #pragma unroll
    for (int tix = 0; tix < 4; ++tix){
        const int R0 = (blockIdx.x * 4 + tix) * 16;          // flat row = i*256 + b
        bf16x8 av[8];
        #pragma unroll
        for (int ks = 0; ks < 8; ++ks)
            av[ks] = *(const bf16x8*)(astate + (size_t)(R0 + l15) * 256 + ks * 32 + q * 8);
        f32x4 acc[4];
        #pragma unroll
        for (int nt = 0; nt < 4; ++nt) acc[nt] = (f32x4){biasy[nt], biasy[nt], biasy[nt], biasy[nt]};
        #pragma unroll
        for (int ks = 0; ks < 8; ++ks)
            #pragma unroll
            for (int nt = 0; nt < 4; ++nt) acc[nt] = MFMA16(av[ks], bwy[nt][ks], acc[nt]);
        #pragma unroll
        for (int nt = 0; nt < 4; ++nt)
            #pragma unroll
            for (int r = 0; r < 4; ++r){
                const int R = R0 + q * 4 + r;
                const int ii = R >> 8, b = R & 255;
                out[((size_t)b * 64 + ii) * 256 + w * 64 + nt * 16 + l15]
                    = __builtin_amdgcn_rcpf(1.0f + __builtin_amdgcn_exp2f(acc[nt][r]));
            }
    }
}

extern "C" void kernel_launch(void* const* d_in, const int* in_sizes, int n_in,
                              void* d_out, int out_size, void* d_ws, size_t ws_size,
                              hipStream_t stream) {
    const float* x   = (const float*)d_in[0];
    const float* w1x = (const float*)d_in[1];
    const float* b1x = (const float*)d_in[2];
    const float* w1a = (const float*)d_in[3];
    const float* b1a = (const float*)d_in[4];
    const float* w2x = (const float*)d_in[5];
    const float* b2x = (const float*)d_in[6];
    const float* w2a = (const float*)d_in[7];
    const float* b2a = (const float*)d_in[8];
    const float* wy  = (const float*)d_in[9];
    const float* by  = (const float*)d_in[10];

    u16*   xpre   = (u16*)d_ws;                     // 64 MiB (k1->k2), then reused:
    u16*   astate = (u16*)d_ws;                     // 8 MiB (k3a->k3b), aliases xpre (k2 done)
    u16*   alast  = xpre + (size_t)512 * 16 * 512 * 8;
    float* injws  = (float*)(alast + 256 * 256);    // 16K f32
    float* o      = (float*)d_out;

    k1_xw <<<512, 256, 0, stream>>>(x, w1x, b1x, b1a, xpre);
    k2_enc<<<16,  256, 0, stream>>>(w1a, xpre, alast);
    k3_pre<<<16,  256, 0, stream>>>(wy, by, w2x, alast, injws);
    k3_rec<<<16,  256, 0, stream>>>(w2a, b2x, b2a, alast, injws, astate);
    k3_out<<<256, 256, 0, stream>>>(wy, by, astate, o);
}